// Round 2
// baseline (631.740 us; speedup 1.0000x reference)
//
#include <hip/hip_runtime.h>
#include <hip/hip_bf16.h>
#include <cstdint>
#include <cstddef>

#define NEG_SLOPE 0.2f

static constexpr int Gg = 2;
static constexpr int Nn = 20000;
static constexpr int Ee = 160000;
static constexpr int Ff = 128;
static constexpr int Cc = 64;
static constexpr int HC = 512;
static constexpr int GN = Gg * Nn;

// ---------- helpers ----------
__device__ __forceinline__ float bf2f(unsigned short b) {
    return __uint_as_float(((unsigned)b) << 16);
}
__device__ __forceinline__ unsigned short f2bf(float x) {
    unsigned u = __float_as_uint(x);
    unsigned r = 0x7fffu + ((u >> 16) & 1u);
    return (unsigned short)((u + r) >> 16);
}
__device__ __forceinline__ void unpack8(const uint4 p, float* f) {
    f[0] = __uint_as_float(p.x << 16); f[1] = __uint_as_float(p.x & 0xffff0000u);
    f[2] = __uint_as_float(p.y << 16); f[3] = __uint_as_float(p.y & 0xffff0000u);
    f[4] = __uint_as_float(p.z << 16); f[5] = __uint_as_float(p.z & 0xffff0000u);
    f[6] = __uint_as_float(p.w << 16); f[7] = __uint_as_float(p.w & 0xffff0000u);
}
// monotonic float<->uint encoding for atomicMax on floats (valid for all non-NaN)
__device__ __forceinline__ unsigned encf(float x) {
    unsigned u = __float_as_uint(x);
    return (u & 0x80000000u) ? ~u : (u | 0x80000000u);
}
__device__ __forceinline__ float decf(unsigned e) {
    return __uint_as_float((e & 0x80000000u) ? (e ^ 0x80000000u) : ~e);
}

// ---------- 1. init ----------
__global__ void zero_init_k(int* cnt, float* lsum, unsigned* gmax) {
    int idx = blockIdx.x * 256 + threadIdx.x;
    if (idx < GN) { cnt[idx] = 0; lsum[idx] = 0.f; }
    if (idx < 64) gmax[idx] = 0u;
}

// ---------- 2. histogram over dst + sum of edge weights per dst ----------
__global__ void hist_k(const int* __restrict__ ei, const float* __restrict__ ew,
                       int* __restrict__ cnt, float* __restrict__ lsum) {
    int idx = blockIdx.x * 256 + threadIdx.x;
    if (idx >= Gg * Ee) return;
    int g = idx / Ee;
    int e = idx - g * Ee;
    int dst = ei[(size_t)g * 2 * Ee + Ee + e];
    float wv = ew[idx];
    atomicAdd(&cnt[g * Nn + dst], 1);
    atomicAdd(&lsum[g * Nn + dst], wv);
}

// ---------- 3. per-graph exclusive scan -> CSR offsets, cursor, loop weight ----------
__global__ __launch_bounds__(1024) void scan_k(const int* __restrict__ cnt, const float* __restrict__ lsum,
                                               int* __restrict__ off, int* __restrict__ cur,
                                               float* __restrict__ loopw) {
    const int g = blockIdx.x;
    const int t = threadIdx.x;
    const int CH = 20; // 1024*20 >= 20000
    int base = t * CH;
    int s = 0;
    for (int k = 0; k < CH; ++k) {
        int i = base + k;
        if (i < Nn) s += cnt[g * Nn + i];
    }
    __shared__ int sh[1024];
    sh[t] = s;
    __syncthreads();
    for (int d = 1; d < 1024; d <<= 1) {
        int v = (t >= d) ? sh[t - d] : 0;
        __syncthreads();
        sh[t] += v;
        __syncthreads();
    }
    int run = sh[t] - s; // exclusive prefix
    for (int k = 0; k < CH; ++k) {
        int i = base + k;
        if (i < Nn) {
            int c = cnt[g * Nn + i];
            off[g * Nn + i] = run;
            cur[g * Nn + i] = run;
            float cn = c > 0 ? (float)c : 1.f;
            loopw[g * Nn + i] = lsum[g * Nn + i] / cn;
            run += c;
        }
    }
}

// ---------- 4. counting-sort scatter of edges by dst ----------
__global__ void scatter_k(const int* __restrict__ ei, const float* __restrict__ ew,
                          int* __restrict__ cur, int2* __restrict__ sedge) {
    int idx = blockIdx.x * 256 + threadIdx.x;
    if (idx >= Gg * Ee) return;
    int g = idx / Ee;
    int e = idx - g * Ee;
    int src = ei[(size_t)g * 2 * Ee + e];
    int dst = ei[(size_t)g * 2 * Ee + Ee + e];
    float wv = ew[idx];
    int pos = atomicAdd(&cur[g * Nn + dst], 1);
    int2 v; v.x = src; v.y = __float_as_int(wv);
    sedge[(size_t)g * Ee + pos] = v;
}

// ---------- GEMM: Y(bf16) = A(MxK) @ W(KxNc) + bias ----------
__device__ __forceinline__ float4 ldA4(const float* p) { return *(const float4*)p; }
__device__ __forceinline__ float4 ldA4(const unsigned short* p) {
    uint2 u = *(const uint2*)p;
    float4 v;
    v.x = __uint_as_float(u.x << 16); v.y = __uint_as_float(u.x & 0xffff0000u);
    v.z = __uint_as_float(u.y << 16); v.w = __uint_as_float(u.y & 0xffff0000u);
    return v;
}

template <typename AT>
__global__ __launch_bounds__(256) void gemm_bias_k(const AT* __restrict__ A, const float* __restrict__ W,
                                                   const float* __restrict__ bias, unsigned short* __restrict__ Y,
                                                   int M, int K, int Nc) {
    __shared__ float Ast[32][68]; // [k][m], padded, float4-aligned
    __shared__ float Bs[32][64];  // [k][n]
    const int t = threadIdx.x;
    const int m0 = blockIdx.x * 64;
    const int n0 = blockIdx.y * 64;
    const int tr = t >> 4, tc = t & 15;
    float acc[4][4] = {};
    for (int k0 = 0; k0 < K; k0 += 32) {
#pragma unroll
        for (int it = 0; it < 2; ++it) {
            int id = t + it * 256;
            int row = id >> 3;
            int kk = (id & 7) * 4;
            float4 v = ldA4(A + (size_t)(m0 + row) * K + k0 + kk);
            Ast[kk + 0][row] = v.x; Ast[kk + 1][row] = v.y;
            Ast[kk + 2][row] = v.z; Ast[kk + 3][row] = v.w;
        }
#pragma unroll
        for (int it = 0; it < 2; ++it) {
            int id = t + it * 256;
            int rb = id >> 4;
            int cg = (id & 15) * 4;
            *(float4*)&Bs[rb][cg] = *(const float4*)(W + (size_t)(k0 + rb) * Nc + n0 + cg);
        }
        __syncthreads();
#pragma unroll
        for (int kk = 0; kk < 32; ++kk) {
            float4 a4 = *(const float4*)&Ast[kk][tr * 4];
            float4 b4 = *(const float4*)&Bs[kk][tc * 4];
            float aa[4] = {a4.x, a4.y, a4.z, a4.w};
            float bb[4] = {b4.x, b4.y, b4.z, b4.w};
#pragma unroll
            for (int i2 = 0; i2 < 4; ++i2)
#pragma unroll
                for (int j2 = 0; j2 < 4; ++j2)
                    acc[i2][j2] += aa[i2] * bb[j2];
        }
        __syncthreads();
    }
    float4 bv = *(const float4*)(bias + n0 + tc * 4);
    float bb[4] = {bv.x, bv.y, bv.z, bv.w};
#pragma unroll
    for (int i2 = 0; i2 < 4; ++i2) {
        int m = m0 + tr * 4 + i2;
        ushort4 ov;
        ov.x = f2bf(acc[i2][0] + bb[0]);
        ov.y = f2bf(acc[i2][1] + bb[1]);
        ov.z = f2bf(acc[i2][2] + bb[2]);
        ov.w = f2bf(acc[i2][3] + bb[3]);
        *(ushort4*)(Y + (size_t)m * Nc + n0 + tc * 4) = ov;
    }
}

// ---------- 5. GATv2 layer-1 aggregation: one wave per node ----------
// lane l owns channels v = 8l..8l+7 (head = l>>3). Online softmax per head.
// NOTE: h1 may alias xr: each xr row is read only by its owning wave before
// that wave writes the same h1 row; no cross-wave access to xr rows.
__global__ __launch_bounds__(256) void agg1_k(const unsigned short* __restrict__ xl,
                                              const unsigned short* __restrict__ xr,
                                              const int2* __restrict__ sedge,
                                              const int* __restrict__ off, const int* __restrict__ cnt,
                                              const float* __restrict__ loopw,
                                              const float* __restrict__ att1, const float* __restrict__ We1,
                                              const float* __restrict__ bias1,
                                              unsigned short* __restrict__ h1) {
    const int lane = threadIdx.x & 63;
    const int wid = (blockIdx.x << 2) + (threadIdx.x >> 6);
    if (wid >= GN) return;
    const int g = wid / Nn;

    float attv[8], wev[8];
    {
        float4 a0 = *(const float4*)(att1 + lane * 8);
        float4 a1 = *(const float4*)(att1 + lane * 8 + 4);
        attv[0] = a0.x; attv[1] = a0.y; attv[2] = a0.z; attv[3] = a0.w;
        attv[4] = a1.x; attv[5] = a1.y; attv[6] = a1.z; attv[7] = a1.w;
        float4 w0 = *(const float4*)(We1 + lane * 8);
        float4 w1 = *(const float4*)(We1 + lane * 8 + 4);
        wev[0] = w0.x; wev[1] = w0.y; wev[2] = w0.z; wev[3] = w0.w;
        wev[4] = w1.x; wev[5] = w1.y; wev[6] = w1.z; wev[7] = w1.w;
    }
    float xrv[8];
    unpack8(((const uint4*)(xr + (size_t)wid * HC))[lane], xrv);

    float m, lsum, acc[8];
    { // self loop: src = i, weight = loopw
        float wv = loopw[wid];
        float xv[8];
        unpack8(((const uint4*)(xl + (size_t)wid * HC))[lane], xv);
        float tp = 0.f;
#pragma unroll
        for (int j = 0; j < 8; ++j) {
            float s = xv[j] + xrv[j] + wv * wev[j];
            s = s > 0.f ? s : NEG_SLOPE * s;
            tp += s * attv[j];
        }
        tp += __shfl_xor(tp, 1); tp += __shfl_xor(tp, 2); tp += __shfl_xor(tp, 4);
        m = tp; lsum = 1.f;
#pragma unroll
        for (int j = 0; j < 8; ++j) acc[j] = xv[j];
    }
    const int e0 = off[wid], ec = cnt[wid];
    const int2* ep = sedge + (size_t)g * Ee + e0;
    for (int e = 0; e < ec; ++e) {
        int2 sd = ep[e];
        int src = sd.x;
        float wv = __int_as_float(sd.y);
        float xv[8];
        unpack8(((const uint4*)(xl + (size_t)(g * Nn + src) * HC))[lane], xv);
        float tp = 0.f;
#pragma unroll
        for (int j = 0; j < 8; ++j) {
            float s = xv[j] + xrv[j] + wv * wev[j];
            s = s > 0.f ? s : NEG_SLOPE * s;
            tp += s * attv[j];
        }
        tp += __shfl_xor(tp, 1); tp += __shfl_xor(tp, 2); tp += __shfl_xor(tp, 4);
        float nm = fmaxf(m, tp);
        float p = __expf(tp - nm);
        float sc = __expf(m - nm);
        lsum = lsum * sc + p;
#pragma unroll
        for (int j = 0; j < 8; ++j) acc[j] = acc[j] * sc + p * xv[j];
        m = nm;
    }
    float inv = 1.f / lsum;
    float4 b0 = *(const float4*)(bias1 + lane * 8);
    float4 b1 = *(const float4*)(bias1 + lane * 8 + 4);
    float bvv[8] = {b0.x, b0.y, b0.z, b0.w, b1.x, b1.y, b1.z, b1.w};
    float ov[8];
#pragma unroll
    for (int j = 0; j < 8; ++j) {
        float o = acc[j] * inv + bvv[j];
        ov[j] = o > 0.f ? o : (__expf(o) - 1.f); // ELU
    }
    uint4 pk;
    pk.x = (unsigned)f2bf(ov[0]) | ((unsigned)f2bf(ov[1]) << 16);
    pk.y = (unsigned)f2bf(ov[2]) | ((unsigned)f2bf(ov[3]) << 16);
    pk.z = (unsigned)f2bf(ov[4]) | ((unsigned)f2bf(ov[5]) << 16);
    pk.w = (unsigned)f2bf(ov[6]) | ((unsigned)f2bf(ov[7]) << 16);
    ((uint4*)(h1 + (size_t)wid * HC))[lane] = pk;
}

// ---------- 6. GATv2 layer-2 aggregation: one wave per node, lane = channel ----------
__global__ __launch_bounds__(256) void agg2_k(const unsigned short* __restrict__ xl2,
                                              const unsigned short* __restrict__ xr2,
                                              const int2* __restrict__ sedge,
                                              const int* __restrict__ off, const int* __restrict__ cnt,
                                              const float* __restrict__ loopw,
                                              const float* __restrict__ att2, const float* __restrict__ We2,
                                              const float* __restrict__ bias2,
                                              float* __restrict__ hout) {
    const int lane = threadIdx.x & 63;
    const int wid = (blockIdx.x << 2) + (threadIdx.x >> 6);
    if (wid >= GN) return;
    const int g = wid / Nn;

    float attv = att2[lane];
    float wev = We2[lane];
    float xrv = bf2f(xr2[(size_t)wid * Cc + lane]);

    float m, lsum, acc;
    { // self loop
        float wv = loopw[wid];
        float xv = bf2f(xl2[(size_t)wid * Cc + lane]);
        float s = xv + xrv + wv * wev;
        s = s > 0.f ? s : NEG_SLOPE * s;
        float tp = s * attv;
#pragma unroll
        for (int msk = 1; msk < 64; msk <<= 1) tp += __shfl_xor(tp, msk);
        m = tp; lsum = 1.f; acc = xv;
    }
    const int e0 = off[wid], ec = cnt[wid];
    const int2* ep = sedge + (size_t)g * Ee + e0;
    for (int e = 0; e < ec; ++e) {
        int2 sd = ep[e];
        float wv = __int_as_float(sd.y);
        float xv = bf2f(xl2[((size_t)(g * Nn + sd.x)) * Cc + lane]);
        float s = xv + xrv + wv * wev;
        s = s > 0.f ? s : NEG_SLOPE * s;
        float tp = s * attv;
#pragma unroll
        for (int msk = 1; msk < 64; msk <<= 1) tp += __shfl_xor(tp, msk);
        float nm = fmaxf(m, tp);
        float p = __expf(tp - nm);
        float sc = __expf(m - nm);
        lsum = lsum * sc + p;
        acc = acc * sc + p * xv;
        m = nm;
    }
    float o = acc / lsum + bias2[lane];
    o = o > 0.f ? o : (__expf(o) - 1.f); // ELU
    hout[(size_t)wid * Cc + lane] = o;
}

// ---------- 7. global per-channel max over all (g, n) ----------
__global__ __launch_bounds__(256) void maxred_k(const float* __restrict__ h, unsigned* __restrict__ gmax) {
    int tid = blockIdx.x * 256 + threadIdx.x; // 65536 threads; stride multiple of 64 keeps channel fixed
    float v = -3.0e38f;
    for (size_t idx = tid; idx < (size_t)GN * Cc; idx += 256 * 256) v = fmaxf(v, h[idx]);
    __shared__ float sh[256];
    sh[threadIdx.x] = v;
    __syncthreads();
    if (threadIdx.x < 64) {
        float mm = fmaxf(fmaxf(sh[threadIdx.x], sh[threadIdx.x + 64]),
                         fmaxf(sh[threadIdx.x + 128], sh[threadIdx.x + 192]));
        atomicMax(&gmax[threadIdx.x], encf(mm));
    }
}

// ---------- 8. Gv = relu(max @ Wg + bg); cvec = Gv @ Wn[64:128] + bn ----------
__global__ __launch_bounds__(64) void prep_k(const unsigned* __restrict__ gmax,
                                             const float* __restrict__ Wg, const float* __restrict__ bg,
                                             const float* __restrict__ Wn, const float* __restrict__ bn,
                                             float* __restrict__ cvec) {
    __shared__ float g0[64], g1[64];
    int t = threadIdx.x;
    g0[t] = decf(gmax[t]);
    __syncthreads();
    float a = bg[t];
    for (int c = 0; c < 64; ++c) a += g0[c] * Wg[c * 64 + t];
    g1[t] = fmaxf(a, 0.f);
    __syncthreads();
    float b = bn[t];
    for (int c = 0; c < 64; ++c) b += g1[c] * Wn[(64 + c) * 64 + t];
    cvec[t] = b;
}

// ---------- 9. out = relu(h @ Wn[:64] + cvec) @ Wo + bo  (f32 output!) ----------
__global__ __launch_bounds__(256) void final_k(const float* __restrict__ h, const float* __restrict__ Wn,
                                               const float* __restrict__ cvec, const float* __restrict__ Wo,
                                               const float* __restrict__ bo, float* __restrict__ out) {
    __shared__ float wns[64 * 64];
    for (int k = threadIdx.x; k < 64 * 64; k += 256) wns[k] = Wn[k];
    __syncthreads();
    const int lane = threadIdx.x & 63;
    const int wid = (blockIdx.x << 2) + (threadIdx.x >> 6);
    if (wid >= GN) return;
    float hv = h[(size_t)wid * Cc + lane];
    float inner = 0.f;
#pragma unroll 16
    for (int c = 0; c < 64; ++c) inner += __shfl(hv, c) * wns[c * 64 + lane];
    float v = fmaxf(inner + cvec[lane], 0.f);
    float tacc = v * Wo[lane];
#pragma unroll
    for (int msk = 1; msk < 64; msk <<= 1) tacc += __shfl_xor(tacc, msk);
    if (lane == 0) out[wid] = tacc + bo[0];
}

// ---------- launch ----------
extern "C" void kernel_launch(void* const* d_in, const int* in_sizes, int n_in,
                              void* d_out, int out_size, void* d_ws, size_t ws_size,
                              hipStream_t stream) {
    const float* x     = (const float*)d_in[0];
    const int*   ei    = (const int*)d_in[1];
    const float* ew    = (const float*)d_in[2];
    const float* Wl1   = (const float*)d_in[3];
    const float* bl1v  = (const float*)d_in[4];
    const float* Wr1   = (const float*)d_in[5];
    const float* br1v  = (const float*)d_in[6];
    const float* We1   = (const float*)d_in[7];
    const float* att1  = (const float*)d_in[8];
    const float* bias1 = (const float*)d_in[9];
    const float* Wl2   = (const float*)d_in[10];
    const float* bl2v  = (const float*)d_in[11];
    const float* Wr2   = (const float*)d_in[12];
    const float* br2v  = (const float*)d_in[13];
    const float* We2   = (const float*)d_in[14];
    const float* att2  = (const float*)d_in[15];
    const float* bias2 = (const float*)d_in[16];
    const float* Wg    = (const float*)d_in[17];
    const float* bgv   = (const float*)d_in[18];
    const float* Wn    = (const float*)d_in[19];
    const float* bnv   = (const float*)d_in[20];
    const float* Wo    = (const float*)d_in[21];
    const float* bov   = (const float*)d_in[22];
    float* out = (float*)d_out;

    char* w = (char*)d_ws;
    size_t o = 0;
    auto take = [&](size_t b) -> char* {
        char* p = w + o;
        o += (b + 255) & ~(size_t)255;
        return p;
    };
    // Region A: 40.96 MB — xl1, later reused for xl2/xr2/hbuf
    unsigned short* xl1 = (unsigned short*)take((size_t)GN * HC * 2);
    // Region B: 40.96 MB — xr1, h1 aliases it (safe: per-row read-then-write by owning wave)
    unsigned short* xr1 = (unsigned short*)take((size_t)GN * HC * 2);
    int*    cnt   = (int*)take((size_t)GN * 4);
    float*  lsum  = (float*)take((size_t)GN * 4);
    int*    off   = (int*)take((size_t)GN * 4);
    int*    cur   = (int*)take((size_t)GN * 4);
    float*  loopw = (float*)take((size_t)GN * 4);
    int2*   sedge = (int2*)take((size_t)Gg * Ee * 8);
    unsigned* gmax = (unsigned*)take(256);
    float*  cvec  = (float*)take(256);
    // overlays (lifetimes disjoint in stream order)
    unsigned short* h1  = xr1;                               // GN*512 bf16 (aliases xr1)
    unsigned short* xl2 = xl1;                               // GN*64 bf16
    unsigned short* xr2 = xl1 + (size_t)GN * Cc;             // GN*64 bf16
    float*          hbuf = (float*)(xl1 + (size_t)2 * GN * Cc); // GN*64 f32 (all fit in region A)

    zero_init_k<<<(GN + 255) / 256, 256, 0, stream>>>(cnt, lsum, gmax);
    hist_k<<<(Gg * Ee + 255) / 256, 256, 0, stream>>>(ei, ew, cnt, lsum);
    scan_k<<<Gg, 1024, 0, stream>>>(cnt, lsum, off, cur, loopw);
    scatter_k<<<(Gg * Ee + 255) / 256, 256, 0, stream>>>(ei, ew, cur, sedge);

    gemm_bias_k<float><<<dim3(GN / 64, HC / 64), 256, 0, stream>>>(x, Wl1, bl1v, xl1, GN, Ff, HC);
    gemm_bias_k<float><<<dim3(GN / 64, HC / 64), 256, 0, stream>>>(x, Wr1, br1v, xr1, GN, Ff, HC);

    agg1_k<<<GN / 4, 256, 0, stream>>>(xl1, xr1, sedge, off, cnt, loopw, att1, We1, bias1, h1);

    gemm_bias_k<unsigned short><<<dim3(GN / 64, Cc / 64), 256, 0, stream>>>(h1, Wl2, bl2v, xl2, GN, HC, Cc);
    gemm_bias_k<unsigned short><<<dim3(GN / 64, Cc / 64), 256, 0, stream>>>(h1, Wr2, br2v, xr2, GN, HC, Cc);

    agg2_k<<<GN / 4, 256, 0, stream>>>(xl2, xr2, sedge, off, cnt, loopw, att2, We2, bias2, hbuf);

    maxred_k<<<256, 256, 0, stream>>>(hbuf, gmax);
    prep_k<<<1, 64, 0, stream>>>(gmax, Wg, bgv, Wn, bnv, cvec);
    final_k<<<GN / 4, 256, 0, stream>>>(hbuf, Wn, cvec, Wo, bov, out);

    (void)in_sizes; (void)n_in; (void)out_size; (void)ws_size;
}

// Round 3
// 445.914 us; speedup vs baseline: 1.4167x; 1.4167x over previous
//
#include <hip/hip_runtime.h>
#include <hip/hip_bf16.h>
#include <cstdint>
#include <cstddef>

#define NEG_SLOPE 0.2f

static constexpr int Gg = 2;
static constexpr int Nn = 20000;
static constexpr int Ee = 160000;
static constexpr int Ff = 128;
static constexpr int Cc = 64;
static constexpr int HC = 512;
static constexpr int GN = Gg * Nn;
static constexpr int GNP = 40064;  // GN padded to 128 multiple

typedef __attribute__((ext_vector_type(8))) short short8;
typedef __attribute__((ext_vector_type(4))) float floatx4;

// ---------- helpers ----------
__device__ __forceinline__ float bf2f(unsigned short b) {
    return __uint_as_float(((unsigned)b) << 16);
}
__device__ __forceinline__ unsigned short f2bf(float x) {
    unsigned u = __float_as_uint(x);
    unsigned r = 0x7fffu + ((u >> 16) & 1u);
    return (unsigned short)((u + r) >> 16);
}
__device__ __forceinline__ void unpack8(const uint4 p, float* f) {
    f[0] = __uint_as_float(p.x << 16); f[1] = __uint_as_float(p.x & 0xffff0000u);
    f[2] = __uint_as_float(p.y << 16); f[3] = __uint_as_float(p.y & 0xffff0000u);
    f[4] = __uint_as_float(p.z << 16); f[5] = __uint_as_float(p.z & 0xffff0000u);
    f[6] = __uint_as_float(p.w << 16); f[7] = __uint_as_float(p.w & 0xffff0000u);
}
__device__ __forceinline__ unsigned encf(float x) {
    unsigned u = __float_as_uint(x);
    return (u & 0x80000000u) ? ~u : (u | 0x80000000u);
}
__device__ __forceinline__ float decf(unsigned e) {
    return __uint_as_float((e & 0x80000000u) ? (e ^ 0x80000000u) : ~e);
}

// ---------- 1. init ----------
__global__ void zero_init_k(int* cnt, float* lsum, unsigned* gmax) {
    int idx = blockIdx.x * 256 + threadIdx.x;
    if (idx < GN) { cnt[idx] = 0; lsum[idx] = 0.f; }
    if (idx < 64) gmax[idx] = 0u;
}

// ---------- 2. histogram over dst + sum of edge weights per dst ----------
__global__ void hist_k(const int* __restrict__ ei, const float* __restrict__ ew,
                       int* __restrict__ cnt, float* __restrict__ lsum) {
    int idx = blockIdx.x * 256 + threadIdx.x;
    if (idx >= Gg * Ee) return;
    int g = idx / Ee;
    int e = idx - g * Ee;
    int dst = ei[(size_t)g * 2 * Ee + Ee + e];
    float wv = ew[idx];
    atomicAdd(&cnt[g * Nn + dst], 1);
    atomicAdd(&lsum[g * Nn + dst], wv);
}

// ---------- 3. per-graph exclusive scan -> CSR offsets, cursor, loop weight ----------
__global__ __launch_bounds__(1024) void scan_k(const int* __restrict__ cnt, const float* __restrict__ lsum,
                                               int* __restrict__ off, int* __restrict__ cur,
                                               float* __restrict__ loopw) {
    const int g = blockIdx.x;
    const int t = threadIdx.x;
    const int CH = 20;
    int base = t * CH;
    int s = 0;
    for (int k = 0; k < CH; ++k) {
        int i = base + k;
        if (i < Nn) s += cnt[g * Nn + i];
    }
    __shared__ int sh[1024];
    sh[t] = s;
    __syncthreads();
    for (int d = 1; d < 1024; d <<= 1) {
        int v = (t >= d) ? sh[t - d] : 0;
        __syncthreads();
        sh[t] += v;
        __syncthreads();
    }
    int run = sh[t] - s;
    for (int k = 0; k < CH; ++k) {
        int i = base + k;
        if (i < Nn) {
            int c = cnt[g * Nn + i];
            off[g * Nn + i] = run;
            cur[g * Nn + i] = run;
            float cn = c > 0 ? (float)c : 1.f;
            loopw[g * Nn + i] = lsum[g * Nn + i] / cn;
            run += c;
        }
    }
}

// ---------- 4. counting-sort scatter of edges by dst ----------
__global__ void scatter_k(const int* __restrict__ ei, const float* __restrict__ ew,
                          int* __restrict__ cur, int2* __restrict__ sedge) {
    int idx = blockIdx.x * 256 + threadIdx.x;
    if (idx >= Gg * Ee) return;
    int g = idx / Ee;
    int e = idx - g * Ee;
    int src = ei[(size_t)g * 2 * Ee + e];
    int dst = ei[(size_t)g * 2 * Ee + Ee + e];
    float wv = ew[idx];
    int pos = atomicAdd(&cur[g * Nn + dst], 1);
    int2 v; v.x = src; v.y = __float_as_int(wv);
    sedge[(size_t)g * Ee + pos] = v;
}

// ---------- 5. cast x (fp32) -> xb (bf16), pad rows [GN, GNP) with zeros ----------
__global__ void cast_x_k(const float* __restrict__ x, unsigned short* __restrict__ xb) {
    int t = blockIdx.x * 256 + threadIdx.x;
    size_t base = (size_t)t * 4;
    if (base >= (size_t)GNP * Ff) return;
    ushort4 ov;
    if (base < (size_t)GN * Ff) {
        float4 v = *(const float4*)(x + base);
        ov.x = f2bf(v.x); ov.y = f2bf(v.y); ov.z = f2bf(v.z); ov.w = f2bf(v.w);
    } else {
        ov.x = ov.y = ov.z = ov.w = 0;
    }
    *(ushort4*)(xb + base) = ov;
}

// ---------- 6. weight prep: transpose + concat + cast to bf16, bias concat ----------
// Wt1[n][k] (1024 x 128): n<512 -> Wl1[k][n], else Wr1[k][n-512]
// Wt2[n][k] (128 x 512):  n<64  -> Wl2[k][n], else Wr2[k][n-64]
__global__ void prep_w_k(const float* __restrict__ Wl1, const float* __restrict__ Wr1,
                         const float* __restrict__ bl1, const float* __restrict__ br1,
                         const float* __restrict__ Wl2, const float* __restrict__ Wr2,
                         const float* __restrict__ bl2, const float* __restrict__ br2,
                         unsigned short* __restrict__ Wt1, unsigned short* __restrict__ Wt2,
                         float* __restrict__ b1cat, float* __restrict__ b2cat) {
    int t = blockIdx.x * 256 + threadIdx.x;
    if (t < 1024 * 128) {
        int n = t >> 7, k = t & 127;
        float v = (n < 512) ? Wl1[(size_t)k * 512 + n] : Wr1[(size_t)k * 512 + n - 512];
        Wt1[t] = f2bf(v);
    }
    if (t < 128 * 512) {
        int n = t >> 9, k = t & 511;
        float v = (n < 64) ? Wl2[(size_t)k * 64 + n] : Wr2[(size_t)k * 64 + n - 64];
        Wt2[t] = f2bf(v);
    }
    if (t < 1024) b1cat[t] = (t < 512) ? bl1[t] : br1[t - 512];
    if (t < 128)  b2cat[t] = (t < 64) ? bl2[t] : br2[t - 64];
}

// ---------- 7. MFMA GEMM: C(bf16,[Mreal x Ngrid*128], stride ldc) = A(bf16, lda) @ Bt^T + bias ----------
// Bt is [Ntot][K] row-major bf16 (pre-transposed). 128x128 tile, BK=32, 4 waves of 64x64.
// LDS chunk swizzle: slot(row, s) holds global chunk (row, c) with c = s ^ ((row>>1)&3).
template <int K>
__global__ __launch_bounds__(256) void mfma_gemm_k(const unsigned short* __restrict__ A, int lda,
                                                   const unsigned short* __restrict__ Bt,
                                                   const float* __restrict__ bias,
                                                   unsigned short* __restrict__ Cg, int ldc,
                                                   int Mreal) {
    __shared__ unsigned short As[128 * 32];
    __shared__ unsigned short Bs[128 * 32];
    const int t = threadIdx.x;
    const int lane = t & 63;
    const int wid = t >> 6;
    const int wm = wid >> 1, wn = wid & 1;
    const int m0 = blockIdx.x * 128;
    const int n0 = blockIdx.y * 128;

    floatx4 acc[4][4] = {};

    const int jrow = t >> 2;          // staging row for round 0 (0..63)
    const int js = t & 3;             // staging slot col
    const int wavebase = (t & 192) * 16; // bytes: wave-uniform LDS base offset

    for (int k0 = 0; k0 < K; k0 += 32) {
#pragma unroll
        for (int r = 0; r < 2; ++r) {
            int row = jrow + r * 64;
            int c = js ^ ((row >> 1) & 3);
            const unsigned short* gA = A + (size_t)(m0 + row) * lda + k0 + c * 8;
            const unsigned short* gB = Bt + (size_t)(n0 + row) * K + k0 + c * 8;
            __builtin_amdgcn_global_load_lds(
                (const __attribute__((address_space(1))) void*)gA,
                (__attribute__((address_space(3))) void*)((char*)As + r * 4096 + wavebase),
                16, 0, 0);
            __builtin_amdgcn_global_load_lds(
                (const __attribute__((address_space(1))) void*)gB,
                (__attribute__((address_space(3))) void*)((char*)Bs + r * 4096 + wavebase),
                16, 0, 0);
        }
        __syncthreads();

        const int lrow = lane & 15, lc = lane >> 4;
        short8 af[4], bf[4];
#pragma unroll
        for (int i2 = 0; i2 < 4; ++i2) {
            int rA = wm * 64 + i2 * 16 + lrow;
            int sA = lc ^ ((rA >> 1) & 3);
            af[i2] = *(const short8*)((const char*)As + (rA * 4 + sA) * 16);
        }
#pragma unroll
        for (int j2 = 0; j2 < 4; ++j2) {
            int rB = wn * 64 + j2 * 16 + lrow;
            int sB = lc ^ ((rB >> 1) & 3);
            bf[j2] = *(const short8*)((const char*)Bs + (rB * 4 + sB) * 16);
        }
#pragma unroll
        for (int i2 = 0; i2 < 4; ++i2)
#pragma unroll
            for (int j2 = 0; j2 < 4; ++j2)
                acc[i2][j2] = __builtin_amdgcn_mfma_f32_16x16x32_bf16(af[i2], bf[j2], acc[i2][j2], 0, 0, 0);
        __syncthreads();
    }

    // epilogue: C layout col = lane&15, row = (lane>>4)*4 + q
    const int col0 = n0 + wn * 64 + (lane & 15);
    const int rowq = (lane >> 4) * 4;
    float bsv[4];
#pragma unroll
    for (int j2 = 0; j2 < 4; ++j2) bsv[j2] = bias[col0 + j2 * 16];
#pragma unroll
    for (int i2 = 0; i2 < 4; ++i2) {
        int mb = m0 + wm * 64 + i2 * 16 + rowq;
#pragma unroll
        for (int q = 0; q < 4; ++q) {
            int m = mb + q;
            if (m < Mreal) {
#pragma unroll
                for (int j2 = 0; j2 < 4; ++j2)
                    Cg[(size_t)m * ldc + col0 + j2 * 16] = f2bf(acc[i2][j2][q] + bsv[j2]);
            }
        }
    }
}

// ---------- 8. GATv2 layer-1 aggregation: one wave per node ----------
// xlr row stride 1024: cols 0..511 = xl (gathered), 512..1023 = xr (row-private).
// h1 output aliases the xr half (read-before-write per row; xl half never written).
__global__ __launch_bounds__(256) void agg1_k(const unsigned short* xlr,
                                              const int2* __restrict__ sedge,
                                              const int* __restrict__ off, const int* __restrict__ cnt,
                                              const float* __restrict__ loopw,
                                              const float* __restrict__ att1, const float* __restrict__ We1,
                                              const float* __restrict__ bias1,
                                              unsigned short* h1) {
    const int lane = threadIdx.x & 63;
    const int wid = (blockIdx.x << 2) + (threadIdx.x >> 6);
    if (wid >= GN) return;
    const int g = wid / Nn;

    float attv[8], wev[8];
    {
        float4 a0 = *(const float4*)(att1 + lane * 8);
        float4 a1 = *(const float4*)(att1 + lane * 8 + 4);
        attv[0] = a0.x; attv[1] = a0.y; attv[2] = a0.z; attv[3] = a0.w;
        attv[4] = a1.x; attv[5] = a1.y; attv[6] = a1.z; attv[7] = a1.w;
        float4 w0 = *(const float4*)(We1 + lane * 8);
        float4 w1 = *(const float4*)(We1 + lane * 8 + 4);
        wev[0] = w0.x; wev[1] = w0.y; wev[2] = w0.z; wev[3] = w0.w;
        wev[4] = w1.x; wev[5] = w1.y; wev[6] = w1.z; wev[7] = w1.w;
    }
    float xrv[8];
    unpack8(((const uint4*)(xlr + (size_t)wid * 1024 + 512))[lane], xrv);

    float m, lsum, acc[8];
    {
        float wv = loopw[wid];
        float xv[8];
        unpack8(((const uint4*)(xlr + (size_t)wid * 1024))[lane], xv);
        float tp = 0.f;
#pragma unroll
        for (int j = 0; j < 8; ++j) {
            float s = xv[j] + xrv[j] + wv * wev[j];
            s = s > 0.f ? s : NEG_SLOPE * s;
            tp += s * attv[j];
        }
        tp += __shfl_xor(tp, 1); tp += __shfl_xor(tp, 2); tp += __shfl_xor(tp, 4);
        m = tp; lsum = 1.f;
#pragma unroll
        for (int j = 0; j < 8; ++j) acc[j] = xv[j];
    }
    const int e0 = off[wid], ec = cnt[wid];
    const int2* ep = sedge + (size_t)g * Ee + e0;
    for (int e = 0; e < ec; ++e) {
        int2 sd = ep[e];
        int src = sd.x;
        float wv = __int_as_float(sd.y);
        float xv[8];
        unpack8(((const uint4*)(xlr + (size_t)(g * Nn + src) * 1024))[lane], xv);
        float tp = 0.f;
#pragma unroll
        for (int j = 0; j < 8; ++j) {
            float s = xv[j] + xrv[j] + wv * wev[j];
            s = s > 0.f ? s : NEG_SLOPE * s;
            tp += s * attv[j];
        }
        tp += __shfl_xor(tp, 1); tp += __shfl_xor(tp, 2); tp += __shfl_xor(tp, 4);
        float nm = fmaxf(m, tp);
        float p = __expf(tp - nm);
        float sc = __expf(m - nm);
        lsum = lsum * sc + p;
#pragma unroll
        for (int j = 0; j < 8; ++j) acc[j] = acc[j] * sc + p * xv[j];
        m = nm;
    }
    float inv = 1.f / lsum;
    float4 b0 = *(const float4*)(bias1 + lane * 8);
    float4 b1 = *(const float4*)(bias1 + lane * 8 + 4);
    float bvv[8] = {b0.x, b0.y, b0.z, b0.w, b1.x, b1.y, b1.z, b1.w};
    float ov[8];
#pragma unroll
    for (int j = 0; j < 8; ++j) {
        float o = acc[j] * inv + bvv[j];
        ov[j] = o > 0.f ? o : (__expf(o) - 1.f);
    }
    uint4 pk;
    pk.x = (unsigned)f2bf(ov[0]) | ((unsigned)f2bf(ov[1]) << 16);
    pk.y = (unsigned)f2bf(ov[2]) | ((unsigned)f2bf(ov[3]) << 16);
    pk.z = (unsigned)f2bf(ov[4]) | ((unsigned)f2bf(ov[5]) << 16);
    pk.w = (unsigned)f2bf(ov[6]) | ((unsigned)f2bf(ov[7]) << 16);
    ((uint4*)(h1 + (size_t)wid * 1024))[lane] = pk;
}

// ---------- 9. GATv2 layer-2 aggregation ----------
// xlr2 row stride 128: cols 0..63 = xl2 (gathered), 64..127 = xr2 (row-private).
__global__ __launch_bounds__(256) void agg2_k(const unsigned short* __restrict__ xlr2,
                                              const int2* __restrict__ sedge,
                                              const int* __restrict__ off, const int* __restrict__ cnt,
                                              const float* __restrict__ loopw,
                                              const float* __restrict__ att2, const float* __restrict__ We2,
                                              const float* __restrict__ bias2,
                                              float* __restrict__ hout) {
    const int lane = threadIdx.x & 63;
    const int wid = (blockIdx.x << 2) + (threadIdx.x >> 6);
    if (wid >= GN) return;
    const int g = wid / Nn;

    float attv = att2[lane];
    float wev = We2[lane];
    float xrv = bf2f(xlr2[(size_t)wid * 128 + 64 + lane]);

    float m, lsum, acc;
    {
        float wv = loopw[wid];
        float xv = bf2f(xlr2[(size_t)wid * 128 + lane]);
        float s = xv + xrv + wv * wev;
        s = s > 0.f ? s : NEG_SLOPE * s;
        float tp = s * attv;
#pragma unroll
        for (int msk = 1; msk < 64; msk <<= 1) tp += __shfl_xor(tp, msk);
        m = tp; lsum = 1.f; acc = xv;
    }
    const int e0 = off[wid], ec = cnt[wid];
    const int2* ep = sedge + (size_t)g * Ee + e0;
    for (int e = 0; e < ec; ++e) {
        int2 sd = ep[e];
        float wv = __int_as_float(sd.y);
        float xv = bf2f(xlr2[((size_t)(g * Nn + sd.x)) * 128 + lane]);
        float s = xv + xrv + wv * wev;
        s = s > 0.f ? s : NEG_SLOPE * s;
        float tp = s * attv;
#pragma unroll
        for (int msk = 1; msk < 64; msk <<= 1) tp += __shfl_xor(tp, msk);
        float nm = fmaxf(m, tp);
        float p = __expf(tp - nm);
        float sc = __expf(m - nm);
        lsum = lsum * sc + p;
        acc = acc * sc + p * xv;
        m = nm;
    }
    float o = acc / lsum + bias2[lane];
    o = o > 0.f ? o : (__expf(o) - 1.f);
    hout[(size_t)wid * Cc + lane] = o;
}

// ---------- 10. global per-channel max ----------
__global__ __launch_bounds__(256) void maxred_k(const float* __restrict__ h, unsigned* __restrict__ gmax) {
    int tid = blockIdx.x * 256 + threadIdx.x;
    float v = -3.0e38f;
    for (size_t idx = tid; idx < (size_t)GN * Cc; idx += 256 * 256) v = fmaxf(v, h[idx]);
    __shared__ float sh[256];
    sh[threadIdx.x] = v;
    __syncthreads();
    if (threadIdx.x < 64) {
        float mm = fmaxf(fmaxf(sh[threadIdx.x], sh[threadIdx.x + 64]),
                         fmaxf(sh[threadIdx.x + 128], sh[threadIdx.x + 192]));
        atomicMax(&gmax[threadIdx.x], encf(mm));
    }
}

// ---------- 11. Gv = relu(max @ Wg + bg); cvec = Gv @ Wn[64:128] + bn ----------
__global__ __launch_bounds__(64) void prep_k(const unsigned* __restrict__ gmax,
                                             const float* __restrict__ Wg, const float* __restrict__ bg,
                                             const float* __restrict__ Wn, const float* __restrict__ bn,
                                             float* __restrict__ cvec) {
    __shared__ float g0[64], g1[64];
    int t = threadIdx.x;
    g0[t] = decf(gmax[t]);
    __syncthreads();
    float a = bg[t];
    for (int c = 0; c < 64; ++c) a += g0[c] * Wg[c * 64 + t];
    g1[t] = fmaxf(a, 0.f);
    __syncthreads();
    float b = bn[t];
    for (int c = 0; c < 64; ++c) b += g1[c] * Wn[(64 + c) * 64 + t];
    cvec[t] = b;
}

// ---------- 12. out = relu(h @ Wn[:64] + cvec) @ Wo + bo  (f32 output) ----------
__global__ __launch_bounds__(256) void final_k(const float* __restrict__ h, const float* __restrict__ Wn,
                                               const float* __restrict__ cvec, const float* __restrict__ Wo,
                                               const float* __restrict__ bo, float* __restrict__ out) {
    __shared__ float wns[64 * 64];
    for (int k = threadIdx.x; k < 64 * 64; k += 256) wns[k] = Wn[k];
    __syncthreads();
    const int lane = threadIdx.x & 63;
    const int wid = (blockIdx.x << 2) + (threadIdx.x >> 6);
    if (wid >= GN) return;
    float hv = h[(size_t)wid * Cc + lane];
    float inner = 0.f;
#pragma unroll 16
    for (int c = 0; c < 64; ++c) inner += __shfl(hv, c) * wns[c * 64 + lane];
    float v = fmaxf(inner + cvec[lane], 0.f);
    float tacc = v * Wo[lane];
#pragma unroll
    for (int msk = 1; msk < 64; msk <<= 1) tacc += __shfl_xor(tacc, msk);
    if (lane == 0) out[wid] = tacc + bo[0];
}

// ---------- launch ----------
extern "C" void kernel_launch(void* const* d_in, const int* in_sizes, int n_in,
                              void* d_out, int out_size, void* d_ws, size_t ws_size,
                              hipStream_t stream) {
    const float* x     = (const float*)d_in[0];
    const int*   ei    = (const int*)d_in[1];
    const float* ew    = (const float*)d_in[2];
    const float* Wl1   = (const float*)d_in[3];
    const float* bl1v  = (const float*)d_in[4];
    const float* Wr1   = (const float*)d_in[5];
    const float* br1v  = (const float*)d_in[6];
    const float* We1   = (const float*)d_in[7];
    const float* att1  = (const float*)d_in[8];
    const float* bias1 = (const float*)d_in[9];
    const float* Wl2   = (const float*)d_in[10];
    const float* bl2v  = (const float*)d_in[11];
    const float* Wr2   = (const float*)d_in[12];
    const float* br2v  = (const float*)d_in[13];
    const float* We2   = (const float*)d_in[14];
    const float* att2  = (const float*)d_in[15];
    const float* bias2 = (const float*)d_in[16];
    const float* Wg    = (const float*)d_in[17];
    const float* bgv   = (const float*)d_in[18];
    const float* Wn    = (const float*)d_in[19];
    const float* bnv   = (const float*)d_in[20];
    const float* Wo    = (const float*)d_in[21];
    const float* bov   = (const float*)d_in[22];
    float* out = (float*)d_out;

    char* w = (char*)d_ws;
    size_t o = 0;
    auto take = [&](size_t b) -> char* {
        char* p = w + o;
        o += (b + 255) & ~(size_t)255;
        return p;
    };
    // xlr1: [GNP][1024] bf16. cols 0..511 = xl1, 512..1023 = xr1, later h1 aliases xr half.
    unsigned short* xlr1 = (unsigned short*)take((size_t)GNP * 1024 * 2); // 82.05 MB
    // xb: [GNP][128] bf16 A-matrix for gemm1; later reused as hbuf (GN*64 f32 = 10.24 MB).
    unsigned short* xb   = (unsigned short*)take((size_t)GNP * Ff * 2);   // 10.26 MB
    // xlr2: [GNP][128] bf16: cols 0..63 = xl2, 64..127 = xr2.
    unsigned short* xlr2 = (unsigned short*)take((size_t)GNP * 128 * 2);  // 10.26 MB
    unsigned short* Wt1  = (unsigned short*)take(1024 * 128 * 2);
    unsigned short* Wt2  = (unsigned short*)take(128 * 512 * 2);
    float* b1cat = (float*)take(1024 * 4);
    float* b2cat = (float*)take(128 * 4);
    int*    cnt   = (int*)take((size_t)GN * 4);
    float*  lsum  = (float*)take((size_t)GN * 4);
    int*    off   = (int*)take((size_t)GN * 4);
    int*    cur   = (int*)take((size_t)GN * 4);
    float*  loopw = (float*)take((size_t)GN * 4);
    int2*   sedge = (int2*)take((size_t)Gg * Ee * 8);
    unsigned* gmax = (unsigned*)take(256);
    float*  cvec  = (float*)take(256);
    // overlays
    unsigned short* h1 = xlr1 + 512; // row stride 1024, aliases xr half
    float* hbuf = (float*)xb;        // xb dead after gemm1

    zero_init_k<<<(GN + 255) / 256, 256, 0, stream>>>(cnt, lsum, gmax);
    hist_k<<<(Gg * Ee + 255) / 256, 256, 0, stream>>>(ei, ew, cnt, lsum);
    scan_k<<<Gg, 1024, 0, stream>>>(cnt, lsum, off, cur, loopw);
    scatter_k<<<(Gg * Ee + 255) / 256, 256, 0, stream>>>(ei, ew, cur, sedge);

    cast_x_k<<<((GNP * Ff / 4) + 255) / 256, 256, 0, stream>>>(x, xb);
    prep_w_k<<<(1024 * 128 + 255) / 256, 256, 0, stream>>>(Wl1, Wr1, bl1v, br1v, Wl2, Wr2, bl2v, br2v,
                                                           Wt1, Wt2, b1cat, b2cat);

    // layer-1 fused projection: [GNP x 128] @ [128 x 1024] -> xlr1
    mfma_gemm_k<Ff><<<dim3(GNP / 128, 8), 256, 0, stream>>>(xb, Ff, Wt1, b1cat, xlr1, 1024, GN);

    agg1_k<<<GN / 4, 256, 0, stream>>>(xlr1, sedge, off, cnt, loopw, att1, We1, bias1, h1);

    // layer-2 fused projection: A = h1 (stride 1024, K=512) @ [512 x 128] -> xlr2
    mfma_gemm_k<HC><<<dim3(GNP / 128, 1), 256, 0, stream>>>(h1, 1024, Wt2, b2cat, xlr2, 128, GN);

    agg2_k<<<GN / 4, 256, 0, stream>>>(xlr2, sedge, off, cnt, loopw, att2, We2, bias2, hbuf);

    maxred_k<<<256, 256, 0, stream>>>(hbuf, gmax);
    prep_k<<<1, 64, 0, stream>>>(gmax, Wg, bgv, Wn, bnv, cvec);
    final_k<<<GN / 4, 256, 0, stream>>>(hbuf, Wn, cvec, Wo, bov, out);

    (void)in_sizes; (void)n_in; (void)out_size; (void)ws_size;
}